// Round 5
// baseline (151.406 us; speedup 1.0000x reference)
//
#include <hip/hip_runtime.h>

// Problem constants
#define BB 8
#define QQ 128
#define KK 1024
#define DD 256
#define HH 256

// scoreav split-K: 32 chunks of 32 k
#define KSP 32
#define KCH 32

// proj D-split: 4 quarters of 64
#define ZSP 4
#define RTOT (BB * QQ + BB * KK)          // 9216 rows
#define PSTRIDE ((size_t)RTOT * HH)       // floats per D-quarter buffer

#define TWO_LOG2E     2.8853900817779268f
#define NEG_TWO_LOG2E -2.8853900817779268f

// ---------------------------------------------------------------------------
// K1: Q+K projection. R16: D-SPLIT x4 (z in 0..3, dc = 64z). R15 post-mortem:
// 8x8@256thr/128x128 tile had the right per-block economics (LDS:VALU 1.5:1,
// 0 conflicts) but only ~176 live blocks on 256 CUs -> 1 wave/SIMD ->
// latency-exposed (VALUBusy 13.7%, 42 us = ~4x the 10 us pipe bound).
// z=4 doubles the grid (576, ~352 live -> ~1.4 blocks/CU, LDS cap 2) and
// halves per-block work: one staging phase + 16 dd-steps. Device bounds:
// LDS ~6.4 us, VALU ~4.3 us. Banks unchanged: As rows tr+16i stride 68 ->
// 2-way (free); Ws rows th+16j -> 4 broadcast addrs (free).
// MASK SKIP: K row-tiles fully >= vl[b] -> early out (128-row granularity).
// ---------------------------------------------------------------------------
__global__ __launch_bounds__(256) void proj_kernel(const float* __restrict__ queries,
                                                   const float* __restrict__ keys,
                                                   const float* __restrict__ Wq,
                                                   const float* __restrict__ Wk,
                                                   const int* __restrict__ vlen,
                                                   float* __restrict__ pp) {
    const int r0 = blockIdx.x * 128;
    const bool isQ = (r0 < BB * QQ);
    if (!isQ) {
        const int kb = (r0 - BB * QQ) >> 7;      // 128-row K tiles
        const int b  = kb >> 3;                  // 8 tiles per batch
        const int k0 = (kb & 7) << 7;
        if (k0 >= vlen[b]) return;               // fully masked (vl==0 too)
    }

    __shared__ float As[128][68];  // stride 68: 4r mod 32 banks, <=2-way (free)
    __shared__ float Ws[128][68];
    const int t  = threadIdx.x;                  // 0..255
    const int tr = t & 15;                       // output rows tr + 16i
    const int th = t >> 4;                       // output cols th + 16j
    const int h0 = blockIdx.y * 128;
    const int dc = blockIdx.z * 64;              // D-quarter base
    const float* A = isQ ? (queries + (size_t)r0 * DD)
                         : (keys + (size_t)(r0 - BB * QQ) * DD);
    const float* W = isQ ? Wq : Wk;

    float acc[8][8] = {};

    // stage 128x64 A-tile and W-tile: 8 float4 per array per thread
#pragma unroll
    for (int i = 0; i < 8; ++i) {
        int fi  = t + 256 * i;               // 0..2047
        int row = fi >> 4;                   // 0..127
        int c4  = (fi & 15) << 2;            // 0..60
        *(float4*)&As[row][c4] = *(const float4*)&A[(size_t)row * DD + dc + c4];
        *(float4*)&Ws[row][c4] = *(const float4*)&W[(size_t)(h0 + row) * DD + dc + c4];
    }
    __syncthreads();
#pragma unroll 2
    for (int dd = 0; dd < 64; dd += 4) {
        float4 a4[8], w4[8];
#pragma unroll
        for (int i = 0; i < 8; ++i) a4[i] = *(float4*)&As[tr + 16 * i][dd];
#pragma unroll
        for (int j = 0; j < 8; ++j) w4[j] = *(float4*)&Ws[th + 16 * j][dd];
#pragma unroll
        for (int i = 0; i < 8; ++i)
#pragma unroll
            for (int j = 0; j < 8; ++j) {
                acc[i][j] += a4[i].x * w4[j].x + a4[i].y * w4[j].y +
                             a4[i].z * w4[j].z + a4[i].w * w4[j].w;
            }
    }

    float* outp = pp + (size_t)blockIdx.z * PSTRIDE;
#pragma unroll
    for (int i = 0; i < 8; ++i)
#pragma unroll
        for (int j = 0; j < 8; ++j) {
            outp[(size_t)(r0 + tr + 16 * i) * HH + h0 + th + 16 * j] =
                TWO_LOG2E * acc[i][j];
        }
}

// ---------------------------------------------------------------------------
// K2: FUSED score + A*V v3. h-sliced 8 waves; staging now combines FOUR proj
// D-quarters: st = exp2(pp0+pp1+pp2+pp3) (4 independent f4 loads per element
// — extra MLP, hides under exp2). Zero barriers in the h-loop, conflict-free
// fragment reads (stride 260 = 4 mod 32), VGPR-bound 4 waves/SIMD.
// Trans/VALU-bound (512 v_rcp_f32 per thread at quarter rate).
// ---------------------------------------------------------------------------
__global__ __launch_bounds__(512, 4) void scoreav_kernel(const float* __restrict__ pp,
                                                         const float* __restrict__ wv,
                                                         const int* __restrict__ vlen,
                                                         const float* __restrict__ V,
                                                         float* __restrict__ partial,
                                                         float* __restrict__ psum) {
    // ---- work-item compaction (uniform scalar scan) ----
    int id = blockIdx.x;
    int b = 0;
    bool found = false;
#pragma unroll
    for (int bb = 0; bb < BB; ++bb) {
        if (!found) {
            int v = vlen[bb];
            int cnt = ((v == 0) ? KSP : ((v + KCH - 1) / KCH)) * 4;
            if (id < cnt) { b = bb; found = true; }
            else id -= cnt;
        }
    }
    if (!found) return;
    const int ksb = id >> 2;
    const int q0  = (id & 3) * 32;
    const int k0  = ksb * KCH;
    const int vl  = vlen[b];

    __shared__ float st[2][32][260];   // [0]=q rows, [1]=k rows; all 256 h. 66.6 KB
    __shared__ float pT[KCH][36];      // [k][q]
    float* red = &st[0][0][0];         // alias: red[w*1056 + q*33 + k] (33.8 KB)

    const int t = threadIdx.x;
    const int w = t >> 6;              // wave 0..7
    const int l = t & 63;
    const int ql = l & 7;              // q rows {ql + 8i}
    const int kl = l >> 3;             // k rows {kl + 8j}

    float acc[4][4] = {};

    if (vl > 0) {
        // stage q (32 rows) + k (32 rows) x 256 h: 4096 f4, 8 per thread;
        // combine 4 D-quarters + exp2 inline. Coalesced 1 KB/wave row reads.
#pragma unroll
        for (int i = 0; i < 8; ++i) {
            int fi  = t + 512 * i;             // 0..4095
            int row = fi >> 6;                 // 0..63
            int c4  = (fi & 63) << 2;          // 0..252
            size_t gr = (row < 32) ? (size_t)(b * QQ + q0 + row)
                                   : (size_t)(BB * QQ + b * KK + k0 + row - 32);
            const float* base = pp + gr * HH + c4;
            float4 v0 = *(const float4*)base;
            float4 v1 = *(const float4*)(base + PSTRIDE);
            float4 v2 = *(const float4*)(base + 2 * PSTRIDE);
            float4 v3 = *(const float4*)(base + 3 * PSTRIDE);
            float4 s;
            s.x = __builtin_amdgcn_exp2f((v0.x + v1.x) + (v2.x + v3.x));
            s.y = __builtin_amdgcn_exp2f((v0.y + v1.y) + (v2.y + v3.y));
            s.z = __builtin_amdgcn_exp2f((v0.z + v1.z) + (v2.z + v3.z));
            s.w = __builtin_amdgcn_exp2f((v0.w + v1.w) + (v2.w + v3.w));
            *(float4*)&st[row >> 5][row & 31][c4] = s;
        }
        __syncthreads();

        const int hw = 32 * w;                 // wave's h window
#pragma unroll
        for (int hh = 0; hh < 32; hh += 4) {
            const float4 w4 = *(const float4*)&wv[hw + hh];   // wave-uniform
            const float* wa = (const float*)&w4;
            float4 q4[4], k4[4];
#pragma unroll
            for (int i = 0; i < 4; ++i) q4[i] = *(float4*)&st[0][ql + 8 * i][hw + hh];
#pragma unroll
            for (int j = 0; j < 4; ++j) k4[j] = *(float4*)&st[1][kl + 8 * j][hw + hh];
#pragma unroll
            for (int i = 0; i < 4; ++i) {
                const float* qa = (const float*)&q4[i];
#pragma unroll
                for (int j = 0; j < 4; ++j) {
                    const float* ka = (const float*)&k4[j];
#pragma unroll
                    for (int c = 0; c < 4; ++c) {
                        float d = __builtin_fmaf(qa[c], ka[c], 1.0f);
                        acc[i][j] += wa[c] * __builtin_amdgcn_rcpf(d);
                    }
                }
            }
        }
        __syncthreads();   // staging dead; red may now overwrite it

        // wave-partial accs -> red
#pragma unroll
        for (int i = 0; i < 4; ++i)
#pragma unroll
            for (int j = 0; j < 4; ++j)
                red[w * 1056 + (ql + 8 * i) * 33 + (kl + 8 * j)] = acc[i][j];
    }
    __syncthreads();

    // ---- combine across waves, masked exp2, pT + psum ----
    float pvv[2];
#pragma unroll
    for (int u = 0; u < 2; ++u) {
        int n = t + 512 * u;               // 0..1023
        int q = n >> 5, k = n & 31;
        float s = 0.f;
        if (vl > 0) {
#pragma unroll
            for (int ww = 0; ww < 8; ++ww) s += red[ww * 1056 + q * 33 + k];
        }
        int kg = k0 + k;
        float pv;
        if (vl == 0) pv = 1.0f;            // uniform row (ref behavior)
        else pv = (kg < vl) ? __builtin_amdgcn_exp2f(NEG_TWO_LOG2E * s) : 0.0f;
        pT[k][q] = pv;
        pvv[u] = pv;
    }
    // psum: lanes 0-31 / 32-63 of each wave share a q; reduce within halves
    float s0 = pvv[0], s1 = pvv[1];
#pragma unroll
    for (int off = 1; off < 32; off <<= 1) {
        s0 += __shfl_xor(s0, off);
        s1 += __shfl_xor(s1, off);
    }
    if ((l & 31) == 0) {
        int qa = 2 * w + (l >> 5);         // q for u=0; u=1 is qa+16
        psum[((size_t)ksb * BB + b) * QQ + q0 + qa]      = s0;
        psum[((size_t)ksb * BB + b) * QQ + q0 + qa + 16] = s1;
    }
    __syncthreads();

    // ---- av phase: thread = (4d x 4q), 8 q-groups over 8 waves ----
    const float* VB = V + ((size_t)b * KK + k0) * DD;
    const int d4 = (t & 63) << 2;
    const int qg = w << 2;                 // 0,4,...,28
    float4 a4[4] = {};
#pragma unroll 4
    for (int k = 0; k < KCH; ++k) {
        float4 v4 = *(const float4*)&VB[(size_t)k * DD + d4];   // coalesced
        float4 p4 = *(float4*)&pT[k][qg];                       // broadcast
        a4[0].x += p4.x * v4.x; a4[0].y += p4.x * v4.y; a4[0].z += p4.x * v4.z; a4[0].w += p4.x * v4.w;
        a4[1].x += p4.y * v4.x; a4[1].y += p4.y * v4.y; a4[1].z += p4.y * v4.z; a4[1].w += p4.y * v4.w;
        a4[2].x += p4.z * v4.x; a4[2].y += p4.z * v4.y; a4[2].z += p4.z * v4.z; a4[2].w += p4.z * v4.w;
        a4[3].x += p4.w * v4.x; a4[3].y += p4.w * v4.y; a4[3].z += p4.w * v4.z; a4[3].w += p4.w * v4.w;
    }
#pragma unroll
    for (int qi = 0; qi < 4; ++qi) {
        int q = q0 + qg + qi;
        *(float4*)&partial[(((size_t)ksb * BB + b) * QQ + q) * DD + d4] = a4[qi];
    }
}

// ---------------------------------------------------------------------------
// K3: mask-aware reduce over the nch(b) live chunks + softmax normalization.
// 4-wide batched reduction (R14): only 1 wave/SIMD exists here (65536 threads
// total), so serial per-chunk loads were latency-exposed. Batch 4 independent
// partial+psum loads per iteration so 4+ loads are in flight per thread.
// ---------------------------------------------------------------------------
__global__ __launch_bounds__(256) void av_reduce(const float* __restrict__ partial,
                                                 const float* __restrict__ psum,
                                                 const int* __restrict__ vlen,
                                                 float* __restrict__ out) {
    const int i  = blockIdx.x * 256 + threadIdx.x;   // float4 index, 65536 total
    const int bq = i >> 6;                           // b*QQ + q
    const int b  = bq >> 7;
    const int vl = vlen[b];
    const int nch = (vl == 0) ? KSP : ((vl + KCH - 1) / KCH);

    const float4* p4 = (const float4*)partial;
    const int stride4 = BB * QQ * DD / 4;            // 65536

    float S = 0.f;
    float4 s = {0.f, 0.f, 0.f, 0.f};
    int ks = 0;
    for (; ks + 4 <= nch; ks += 4) {
        float Sa = psum[(size_t)(ks + 0) * (BB * QQ) + bq];
        float Sb = psum[(size_t)(ks + 1) * (BB * QQ) + bq];
        float Sc = psum[(size_t)(ks + 2) * (BB * QQ) + bq];
        float Sd = psum[(size_t)(ks + 3) * (BB * QQ) + bq];
        float4 x0 = p4[(size_t)(ks + 0) * stride4 + i];
        float4 x1 = p4[(size_t)(ks + 1) * stride4 + i];
        float4 x2 = p4[(size_t)(ks + 2) * stride4 + i];
        float4 x3 = p4[(size_t)(ks + 3) * stride4 + i];
        S += (Sa + Sb) + (Sc + Sd);
        s.x += (x0.x + x1.x) + (x2.x + x3.x);
        s.y += (x0.y + x1.y) + (x2.y + x3.y);
        s.z += (x0.z + x1.z) + (x2.z + x3.z);
        s.w += (x0.w + x1.w) + (x2.w + x3.w);
    }
    for (; ks < nch; ++ks) {
        S += psum[(size_t)ks * (BB * QQ) + bq];
        float4 x = p4[(size_t)ks * stride4 + i];
        s.x += x.x; s.y += x.y; s.z += x.z; s.w += x.w;
    }

    const float inv = 1.0f / S;   // S>0 always: p>=8e-12 unmasked, vl==0 -> p=1
    s.x *= inv; s.y *= inv; s.z *= inv; s.w *= inv;
    ((float4*)out)[i] = s;
}

// ---------------------------------------------------------------------------
extern "C" void kernel_launch(void* const* d_in, const int* in_sizes, int n_in,
                              void* d_out, int out_size, void* d_ws, size_t ws_size,
                              hipStream_t stream) {
    const float* queries = (const float*)d_in[0];   // [B,Q,D]
    const float* keys    = (const float*)d_in[1];   // [B,K,D]
    const float* values  = (const float*)d_in[2];   // [B,K,D]
    const float* W_q     = (const float*)d_in[3];   // [H,D]
    const float* W_k     = (const float*)d_in[4];   // [H,D]
    const float* w_v     = (const float*)d_in[5];   // [H]
    const int*   vlen    = (const int*)d_in[6];     // [B]
    float* out = (float*)d_out;

    float* ws      = (float*)d_ws;
    float* pp      = ws;                                  // ZSP*PSTRIDE = 37.7 MB
    float* psum    = pp + (size_t)ZSP * PSTRIDE;          // KSP*B*Q = 32768
    float* partial = psum + (size_t)KSP * BB * QQ;        // 33.5 MB
    // no aliasing: scoreav reads pp while writing partial. ~71 MB of ws.

    // D-split x4 Q+K projection (pp quarters, no exp2), mask-skipped.
    // 256-thread blocks, 128x128 tile, 8x8 register blocking.
    proj_kernel<<<dim3(RTOT / 128, HH / 128, ZSP), 256, 0, stream>>>(
        queries, keys, W_q, W_k, vlen, pp);

    // Fused score + A*V, h-sliced 8-wave blocks, 4-quarter combine in staging
    scoreav_kernel<<<dim3(KSP * 4 * BB, 1, 1), 512, 0, stream>>>(
        pp, w_v, vlen, values, partial, psum);

    // Mask-aware reduce + softmax normalization (4-wide batched)
    av_reduce<<<dim3(BB * QQ * DD / 4 / 256, 1, 1), 256, 0, stream>>>(
        partial, psum, vlen, out);
}

// Round 6
// 129.638 us; speedup vs baseline: 1.1679x; 1.1679x over previous
//
#include <hip/hip_runtime.h>

// Problem constants
#define BB 8
#define QQ 128
#define KK 1024
#define DD 256
#define HH 256

// scoreav split-K: 32 chunks of 32 k
#define KSP 32
#define KCH 32

// proj D-split: 4 quarters of 64
#define ZSP 4
#define RTOT (BB * QQ + BB * KK)          // 9216 rows
#define PSTRIDE ((size_t)RTOT * HH)       // floats per D-quarter buffer

#define TWO_LOG2E     2.8853900817779268f
#define NEG_TWO_LOG2E -2.8853900817779268f

// ---------------------------------------------------------------------------
// K1: Q+K projection. R17. R16 post-mortem: (a) scattered scalar epilogue
// cost ~19 us (z=4 doubled it: +10.6 us measured, txn model +9.4 predicted);
// (b) VGPR 88 < acc[8][8](64)+frags(64) -> compiler chunked each dd-step into
// serial {ds_read, wait, FMA} with exposed LDS latency (~2400 cyc/step vs 512
// busy -> VALUBusy 12%). Fix: 64r x 128h tile, acc[4][8] (32 regs) so all 12
// fragments batch-load; epilogue bounces acc through dead staging LDS and
// writes 512B-contiguous float4 runs. Grid (144,2,4)=1152, live ~704 -> 2.75
// blocks/CU; LDS 52.2 KB -> 3 blocks/CU cap -> 2-3 waves/SIMD.
// Banks: As rows tr+16i, Ws rows th+16j, stride 68 = 4 mod 32 -> <=2-way
// (free); Ob stride 132 = 4 mod 32 -> 2-way (free).
// MASK SKIP: K row-tiles fully >= vl[b] -> early out (64-row granularity).
// ---------------------------------------------------------------------------
__global__ __launch_bounds__(256) void proj_kernel(const float* __restrict__ queries,
                                                   const float* __restrict__ keys,
                                                   const float* __restrict__ Wq,
                                                   const float* __restrict__ Wk,
                                                   const int* __restrict__ vlen,
                                                   float* __restrict__ pp) {
    const int r0 = blockIdx.x * 64;
    const bool isQ = (r0 < BB * QQ);
    if (!isQ) {
        const int kb = (r0 - BB * QQ) >> 6;      // 64-row K tiles
        const int b  = kb >> 4;                  // 16 tiles per batch
        const int k0 = (kb & 15) << 6;
        if (k0 >= vlen[b]) return;               // fully masked (vl==0 too)
    }

    __shared__ float smem[192 * 68];             // 52.2 KB, carved below
    float (*As)[68] = (float(*)[68])smem;                  // [64][68]
    float (*Ws)[68] = (float(*)[68])(smem + 64 * 68);      // [128][68]

    const int t  = threadIdx.x;                  // 0..255
    const int tr = t & 15;                       // output rows tr + 16i, i<4
    const int th = t >> 4;                       // output cols th + 16j, j<8
    const int h0 = blockIdx.y * 128;
    const int dc = blockIdx.z * 64;              // D-quarter base
    const float* A = isQ ? (queries + (size_t)r0 * DD)
                         : (keys + (size_t)(r0 - BB * QQ) * DD);
    const float* W = isQ ? Wq : Wk;

    // stage As 64x64 (1024 f4) + Ws 128x64 (2048 f4): 12 f4 per thread
#pragma unroll
    for (int i = 0; i < 4; ++i) {
        int fi  = t + 256 * i;                   // 0..1023
        int row = fi >> 4;                       // 0..63
        int c4  = (fi & 15) << 2;                // 0..60
        *(float4*)&As[row][c4] = *(const float4*)&A[(size_t)row * DD + dc + c4];
    }
#pragma unroll
    for (int i = 0; i < 8; ++i) {
        int fi  = t + 256 * i;                   // 0..2047
        int row = fi >> 4;                       // 0..127
        int c4  = (fi & 15) << 2;                // 0..60
        *(float4*)&Ws[row][c4] = *(const float4*)&W[(size_t)(h0 + row) * DD + dc + c4];
    }
    __syncthreads();

    float acc[4][8] = {};
#pragma unroll 2
    for (int dd = 0; dd < 64; dd += 4) {
        float4 a4[4], w4[8];
#pragma unroll
        for (int i = 0; i < 4; ++i) a4[i] = *(float4*)&As[tr + 16 * i][dd];
#pragma unroll
        for (int j = 0; j < 8; ++j) w4[j] = *(float4*)&Ws[th + 16 * j][dd];
#pragma unroll
        for (int i = 0; i < 4; ++i)
#pragma unroll
            for (int j = 0; j < 8; ++j) {
                acc[i][j] += a4[i].x * w4[j].x + a4[i].y * w4[j].y +
                             a4[i].z * w4[j].z + a4[i].w * w4[j].w;
            }
    }
    __syncthreads();                             // staging LDS now dead

    // bounce acc -> LDS (2-way banks, free), then coalesced global write
    float (*Ob)[132] = (float(*)[132])smem;      // [64][132] = 33.8 KB
#pragma unroll
    for (int i = 0; i < 4; ++i)
#pragma unroll
        for (int j = 0; j < 8; ++j)
            Ob[tr + 16 * i][th + 16 * j] = TWO_LOG2E * acc[i][j];
    __syncthreads();

    float* outp = pp + (size_t)blockIdx.z * PSTRIDE + (size_t)r0 * HH + h0;
#pragma unroll
    for (int i = 0; i < 8; ++i) {
        int fi  = t + 256 * i;                   // 0..2047
        int row = fi >> 5;                       // 0..63
        int c4  = (fi & 31) << 2;                // 0..124
        *(float4*)&outp[(size_t)row * HH + c4] = *(float4*)&Ob[row][c4];
    }
}

// ---------------------------------------------------------------------------
// K2: FUSED score + A*V v3 (unchanged from R16). h-sliced 8 waves; staging
// combines FOUR proj D-quarters: st = exp2(pp0+pp1+pp2+pp3) (4 independent
// f4 loads per element — extra MLP, hides under exp2). Zero barriers in the
// h-loop, conflict-free fragment reads (stride 260 = 4 mod 32), VGPR-bound
// 4 waves/SIMD. Trans/VALU-bound (512 v_rcp_f32 per thread at quarter rate).
// ---------------------------------------------------------------------------
__global__ __launch_bounds__(512, 4) void scoreav_kernel(const float* __restrict__ pp,
                                                         const float* __restrict__ wv,
                                                         const int* __restrict__ vlen,
                                                         const float* __restrict__ V,
                                                         float* __restrict__ partial,
                                                         float* __restrict__ psum) {
    // ---- work-item compaction (uniform scalar scan) ----
    int id = blockIdx.x;
    int b = 0;
    bool found = false;
#pragma unroll
    for (int bb = 0; bb < BB; ++bb) {
        if (!found) {
            int v = vlen[bb];
            int cnt = ((v == 0) ? KSP : ((v + KCH - 1) / KCH)) * 4;
            if (id < cnt) { b = bb; found = true; }
            else id -= cnt;
        }
    }
    if (!found) return;
    const int ksb = id >> 2;
    const int q0  = (id & 3) * 32;
    const int k0  = ksb * KCH;
    const int vl  = vlen[b];

    __shared__ float st[2][32][260];   // [0]=q rows, [1]=k rows; all 256 h. 66.6 KB
    __shared__ float pT[KCH][36];      // [k][q]
    float* red = &st[0][0][0];         // alias: red[w*1056 + q*33 + k] (33.8 KB)

    const int t = threadIdx.x;
    const int w = t >> 6;              // wave 0..7
    const int l = t & 63;
    const int ql = l & 7;              // q rows {ql + 8i}
    const int kl = l >> 3;             // k rows {kl + 8j}

    float acc[4][4] = {};

    if (vl > 0) {
        // stage q (32 rows) + k (32 rows) x 256 h: 4096 f4, 8 per thread;
        // combine 4 D-quarters + exp2 inline. Coalesced 1 KB/wave row reads.
#pragma unroll
        for (int i = 0; i < 8; ++i) {
            int fi  = t + 512 * i;             // 0..4095
            int row = fi >> 6;                 // 0..63
            int c4  = (fi & 63) << 2;          // 0..252
            size_t gr = (row < 32) ? (size_t)(b * QQ + q0 + row)
                                   : (size_t)(BB * QQ + b * KK + k0 + row - 32);
            const float* base = pp + gr * HH + c4;
            float4 v0 = *(const float4*)base;
            float4 v1 = *(const float4*)(base + PSTRIDE);
            float4 v2 = *(const float4*)(base + 2 * PSTRIDE);
            float4 v3 = *(const float4*)(base + 3 * PSTRIDE);
            float4 s;
            s.x = __builtin_amdgcn_exp2f((v0.x + v1.x) + (v2.x + v3.x));
            s.y = __builtin_amdgcn_exp2f((v0.y + v1.y) + (v2.y + v3.y));
            s.z = __builtin_amdgcn_exp2f((v0.z + v1.z) + (v2.z + v3.z));
            s.w = __builtin_amdgcn_exp2f((v0.w + v1.w) + (v2.w + v3.w));
            *(float4*)&st[row >> 5][row & 31][c4] = s;
        }
        __syncthreads();

        const int hw = 32 * w;                 // wave's h window
#pragma unroll
        for (int hh = 0; hh < 32; hh += 4) {
            const float4 w4 = *(const float4*)&wv[hw + hh];   // wave-uniform
            const float* wa = (const float*)&w4;
            float4 q4[4], k4[4];
#pragma unroll
            for (int i = 0; i < 4; ++i) q4[i] = *(float4*)&st[0][ql + 8 * i][hw + hh];
#pragma unroll
            for (int j = 0; j < 4; ++j) k4[j] = *(float4*)&st[1][kl + 8 * j][hw + hh];
#pragma unroll
            for (int i = 0; i < 4; ++i) {
                const float* qa = (const float*)&q4[i];
#pragma unroll
                for (int j = 0; j < 4; ++j) {
                    const float* ka = (const float*)&k4[j];
#pragma unroll
                    for (int c = 0; c < 4; ++c) {
                        float d = __builtin_fmaf(qa[c], ka[c], 1.0f);
                        acc[i][j] += wa[c] * __builtin_amdgcn_rcpf(d);
                    }
                }
            }
        }
        __syncthreads();   // staging dead; red may now overwrite it

        // wave-partial accs -> red
#pragma unroll
        for (int i = 0; i < 4; ++i)
#pragma unroll
            for (int j = 0; j < 4; ++j)
                red[w * 1056 + (ql + 8 * i) * 33 + (kl + 8 * j)] = acc[i][j];
    }
    __syncthreads();

    // ---- combine across waves, masked exp2, pT + psum ----
    float pvv[2];
#pragma unroll
    for (int u = 0; u < 2; ++u) {
        int n = t + 512 * u;               // 0..1023
        int q = n >> 5, k = n & 31;
        float s = 0.f;
        if (vl > 0) {
#pragma unroll
            for (int ww = 0; ww < 8; ++ww) s += red[ww * 1056 + q * 33 + k];
        }
        int kg = k0 + k;
        float pv;
        if (vl == 0) pv = 1.0f;            // uniform row (ref behavior)
        else pv = (kg < vl) ? __builtin_amdgcn_exp2f(NEG_TWO_LOG2E * s) : 0.0f;
        pT[k][q] = pv;
        pvv[u] = pv;
    }
    // psum: lanes 0-31 / 32-63 of each wave share a q; reduce within halves
    float s0 = pvv[0], s1 = pvv[1];
#pragma unroll
    for (int off = 1; off < 32; off <<= 1) {
        s0 += __shfl_xor(s0, off);
        s1 += __shfl_xor(s1, off);
    }
    if ((l & 31) == 0) {
        int qa = 2 * w + (l >> 5);         // q for u=0; u=1 is qa+16
        psum[((size_t)ksb * BB + b) * QQ + q0 + qa]      = s0;
        psum[((size_t)ksb * BB + b) * QQ + q0 + qa + 16] = s1;
    }
    __syncthreads();

    // ---- av phase: thread = (4d x 4q), 8 q-groups over 8 waves ----
    const float* VB = V + ((size_t)b * KK + k0) * DD;
    const int d4 = (t & 63) << 2;
    const int qg = w << 2;                 // 0,4,...,28
    float4 a4[4] = {};
#pragma unroll 4
    for (int k = 0; k < KCH; ++k) {
        float4 v4 = *(const float4*)&VB[(size_t)k * DD + d4];   // coalesced
        float4 p4 = *(float4*)&pT[k][qg];                       // broadcast
        a4[0].x += p4.x * v4.x; a4[0].y += p4.x * v4.y; a4[0].z += p4.x * v4.z; a4[0].w += p4.x * v4.w;
        a4[1].x += p4.y * v4.x; a4[1].y += p4.y * v4.y; a4[1].z += p4.y * v4.z; a4[1].w += p4.y * v4.w;
        a4[2].x += p4.z * v4.x; a4[2].y += p4.z * v4.y; a4[2].z += p4.z * v4.z; a4[2].w += p4.z * v4.w;
        a4[3].x += p4.w * v4.x; a4[3].y += p4.w * v4.y; a4[3].z += p4.w * v4.z; a4[3].w += p4.w * v4.w;
    }
#pragma unroll
    for (int qi = 0; qi < 4; ++qi) {
        int q = q0 + qg + qi;
        *(float4*)&partial[(((size_t)ksb * BB + b) * QQ + q) * DD + d4] = a4[qi];
    }
}

// ---------------------------------------------------------------------------
// K3: mask-aware reduce over the nch(b) live chunks + softmax normalization.
// 4-wide batched reduction (R14): only 1 wave/SIMD exists here (65536 threads
// total), so serial per-chunk loads were latency-exposed. Batch 4 independent
// partial+psum loads per iteration so 4+ loads are in flight per thread.
// ---------------------------------------------------------------------------
__global__ __launch_bounds__(256) void av_reduce(const float* __restrict__ partial,
                                                 const float* __restrict__ psum,
                                                 const int* __restrict__ vlen,
                                                 float* __restrict__ out) {
    const int i  = blockIdx.x * 256 + threadIdx.x;   // float4 index, 65536 total
    const int bq = i >> 6;                           // b*QQ + q
    const int b  = bq >> 7;
    const int vl = vlen[b];
    const int nch = (vl == 0) ? KSP : ((vl + KCH - 1) / KCH);

    const float4* p4 = (const float4*)partial;
    const int stride4 = BB * QQ * DD / 4;            // 65536

    float S = 0.f;
    float4 s = {0.f, 0.f, 0.f, 0.f};
    int ks = 0;
    for (; ks + 4 <= nch; ks += 4) {
        float Sa = psum[(size_t)(ks + 0) * (BB * QQ) + bq];
        float Sb = psum[(size_t)(ks + 1) * (BB * QQ) + bq];
        float Sc = psum[(size_t)(ks + 2) * (BB * QQ) + bq];
        float Sd = psum[(size_t)(ks + 3) * (BB * QQ) + bq];
        float4 x0 = p4[(size_t)(ks + 0) * stride4 + i];
        float4 x1 = p4[(size_t)(ks + 1) * stride4 + i];
        float4 x2 = p4[(size_t)(ks + 2) * stride4 + i];
        float4 x3 = p4[(size_t)(ks + 3) * stride4 + i];
        S += (Sa + Sb) + (Sc + Sd);
        s.x += (x0.x + x1.x) + (x2.x + x3.x);
        s.y += (x0.y + x1.y) + (x2.y + x3.y);
        s.z += (x0.z + x1.z) + (x2.z + x3.z);
        s.w += (x0.w + x1.w) + (x2.w + x3.w);
    }
    for (; ks < nch; ++ks) {
        S += psum[(size_t)ks * (BB * QQ) + bq];
        float4 x = p4[(size_t)ks * stride4 + i];
        s.x += x.x; s.y += x.y; s.z += x.z; s.w += x.w;
    }

    const float inv = 1.0f / S;   // S>0 always: p>=8e-12 unmasked, vl==0 -> p=1
    s.x *= inv; s.y *= inv; s.z *= inv; s.w *= inv;
    ((float4*)out)[i] = s;
}

// ---------------------------------------------------------------------------
extern "C" void kernel_launch(void* const* d_in, const int* in_sizes, int n_in,
                              void* d_out, int out_size, void* d_ws, size_t ws_size,
                              hipStream_t stream) {
    const float* queries = (const float*)d_in[0];   // [B,Q,D]
    const float* keys    = (const float*)d_in[1];   // [B,K,D]
    const float* values  = (const float*)d_in[2];   // [B,K,D]
    const float* W_q     = (const float*)d_in[3];   // [H,D]
    const float* W_k     = (const float*)d_in[4];   // [H,D]
    const float* w_v     = (const float*)d_in[5];   // [H]
    const int*   vlen    = (const int*)d_in[6];     // [B]
    float* out = (float*)d_out;

    float* ws      = (float*)d_ws;
    float* pp      = ws;                                  // ZSP*PSTRIDE = 37.7 MB
    float* psum    = pp + (size_t)ZSP * PSTRIDE;          // KSP*B*Q = 32768
    float* partial = psum + (size_t)KSP * BB * QQ;        // 33.5 MB
    // no aliasing: scoreav reads pp while writing partial. ~71 MB of ws.

    // D-split x4 Q+K projection (pp quarters, no exp2), mask-skipped.
    // R17: 64r x 128h tile, 256 threads, acc[4][8], coalesced LDS-bounce
    // epilogue. Grid 1152 blocks.
    proj_kernel<<<dim3(RTOT / 64, HH / 128, ZSP), 256, 0, stream>>>(
        queries, keys, W_q, W_k, vlen, pp);

    // Fused score + A*V, h-sliced 8-wave blocks, 4-quarter combine in staging
    scoreav_kernel<<<dim3(KSP * 4 * BB, 1, 1), 512, 0, stream>>>(
        pp, w_v, vlen, values, partial, psum);

    // Mask-aware reduce + softmax normalization (4-wide batched)
    av_reduce<<<dim3(BB * QQ * DD / 4 / 256, 1, 1), 256, 0, stream>>>(
        partial, psum, vlen, out);
}